// Round 10
// baseline (3762.177 us; speedup 1.0000x reference)
//
#include <hip/hip_runtime.h>
#include <math.h>

namespace {
constexpr int kV = 12001;
constexpr int kE = 300;
constexpr int kR = 1024;
constexpr int kH = 512;
constexpr int kF = 2048;
constexpr int kB = 64;
constexpr int kT = 20;
constexpr int kL = 196;
}

typedef __attribute__((ext_vector_type(8))) short short8;
typedef __attribute__((ext_vector_type(4))) float f32x4;

__device__ __forceinline__ unsigned short f2bf(float f) {
    unsigned u = __builtin_bit_cast(unsigned, f);
    u = (u + 0x7fffu + ((u >> 16) & 1u)) >> 16;
    return (unsigned short)u;
}
__device__ __forceinline__ float bf2f(unsigned short h) {
    unsigned u = ((unsigned)h) << 16;
    return __builtin_bit_cast(float, u);
}
__device__ __forceinline__ float fast_tanh(float x) {
    x = fminf(15.f, fmaxf(-15.f, x));
    const float e = __expf(2.f * x);
    return (e - 1.f) / (e + 1.f);
}
__device__ __forceinline__ float fast_sig(float x) {
    return 1.f / (1.f + __expf(-x));
}

// ---------------------------------------------------------------------------
// fp32 -> bf16-hi conversion (n4 = count/4)
// ---------------------------------------------------------------------------
__global__ __launch_bounds__(256)
void conv_hi_kernel(const float* __restrict__ in, unsigned short* __restrict__ out, int n4)
{
    for (int i = blockIdx.x * 256 + threadIdx.x; i < n4; i += gridDim.x * 256) {
        const float4 v = ((const float4*)in)[i];
        ushort4 o;
        o.x = f2bf(v.x); o.y = f2bf(v.y); o.z = f2bf(v.z); o.w = f2bf(v.w);
        ((ushort4*)out)[i] = o;
    }
}

// fp32 -> (hi, lo) bf16 pair
__global__ __launch_bounds__(256)
void conv_pair_kernel(const float* __restrict__ in,
                      unsigned short* __restrict__ hi_out,
                      unsigned short* __restrict__ lo_out, int n4)
{
    for (int i = blockIdx.x * 256 + threadIdx.x; i < n4; i += gridDim.x * 256) {
        const float4 v = ((const float4*)in)[i];
        ushort4 h, l;
        h.x = f2bf(v.x); l.x = f2bf(v.x - bf2f(h.x));
        h.y = f2bf(v.y); l.y = f2bf(v.y - bf2f(h.y));
        h.z = f2bf(v.z); l.z = f2bf(v.z - bf2f(h.z));
        h.w = f2bf(v.w); l.w = f2bf(v.w - bf2f(h.w));
        ((ushort4*)hi_out)[i] = h;
        ((ushort4*)lo_out)[i] = l;
    }
}

// ---------------------------------------------------------------------------
// bf16-staged MFMA GEMM. products: Ah*Wh + Ah*Wl (+ Al*Wh if A_PAIR).
// ---------------------------------------------------------------------------
template<bool A_PAIR, bool OUT_BF16>
__global__ __launch_bounds__(256)
void gemm_bf_kernel(const unsigned short* __restrict__ Ah,
                    const unsigned short* __restrict__ Al, int lda,
                    const unsigned short* __restrict__ Wh,
                    const unsigned short* __restrict__ Wl, int ldw,
                    const float* __restrict__ bias,
                    void* __restrict__ Cp, int ldc,
                    int M, int N, int K)
{
    __shared__ unsigned short sAh[128][40];
    __shared__ unsigned short sAl[A_PAIR ? 128 : 1][40];
    __shared__ unsigned short sWh[128][40];
    __shared__ unsigned short sWl[128][40];
    const int tid = threadIdx.x;
    const int m0 = blockIdx.y * 128;
    const int n0 = blockIdx.x * 128;
    const int wave = tid >> 6, lane = tid & 63;
    const int wm = wave >> 1, wn = wave & 1;
    const int lrow = lane & 15, lkg = lane >> 4;

    f32x4 acc[4][4];
    #pragma unroll
    for (int mi = 0; mi < 4; ++mi)
        #pragma unroll
        for (int ni = 0; ni < 4; ++ni)
            acc[mi][ni] = (f32x4){0.f, 0.f, 0.f, 0.f};

    for (int k0 = 0; k0 < K; k0 += 32) {
        for (int g = tid; g < 512; g += 256) {
            const int r = g >> 2, q = g & 3;
            const int k = k0 + q * 8;
            const size_t off = (size_t)(m0 + r) * lda + k;
            *(short8*)&sAh[r][q * 8] = *(const short8*)(Ah + off);
            if (A_PAIR) *(short8*)&sAl[r][q * 8] = *(const short8*)(Al + off);
        }
        for (int g = tid; g < 512; g += 256) {
            const int r = g >> 2, q = g & 3;
            const int k = k0 + q * 8;
            const int n = n0 + r;
            short8 vh = (short8){0,0,0,0,0,0,0,0};
            short8 vl = (short8){0,0,0,0,0,0,0,0};
            if (n < N) {
                const size_t off = (size_t)n * ldw + k;
                vh = *(const short8*)(Wh + off);
                vl = *(const short8*)(Wl + off);
            }
            *(short8*)&sWh[r][q * 8] = vh;
            *(short8*)&sWl[r][q * 8] = vl;
        }
        __syncthreads();

        short8 ah[4], al[4], wh[4], wl[4];
        #pragma unroll
        for (int mi = 0; mi < 4; ++mi) {
            ah[mi] = *(const short8*)&sAh[wm * 64 + mi * 16 + lrow][lkg * 8];
            if (A_PAIR) al[mi] = *(const short8*)&sAl[wm * 64 + mi * 16 + lrow][lkg * 8];
        }
        #pragma unroll
        for (int ni = 0; ni < 4; ++ni) {
            wh[ni] = *(const short8*)&sWh[wn * 64 + ni * 16 + lrow][lkg * 8];
            wl[ni] = *(const short8*)&sWl[wn * 64 + ni * 16 + lrow][lkg * 8];
        }
        #pragma unroll
        for (int mi = 0; mi < 4; ++mi)
            #pragma unroll
            for (int ni = 0; ni < 4; ++ni) {
                acc[mi][ni] = __builtin_amdgcn_mfma_f32_16x16x32_bf16(ah[mi], wh[ni], acc[mi][ni], 0, 0, 0);
                acc[mi][ni] = __builtin_amdgcn_mfma_f32_16x16x32_bf16(ah[mi], wl[ni], acc[mi][ni], 0, 0, 0);
                if (A_PAIR)
                    acc[mi][ni] = __builtin_amdgcn_mfma_f32_16x16x32_bf16(al[mi], wh[ni], acc[mi][ni], 0, 0, 0);
            }
        __syncthreads();
    }

    #pragma unroll
    for (int mi = 0; mi < 4; ++mi) {
        const int mbase = m0 + wm * 64 + mi * 16 + lkg * 4;
        #pragma unroll
        for (int ni = 0; ni < 4; ++ni) {
            const int n = n0 + wn * 64 + ni * 16 + lrow;
            if (n >= N) continue;
            const float bb = bias ? bias[n] : 0.f;
            #pragma unroll
            for (int r = 0; r < 4; ++r) {
                const int m = mbase + r;
                const float v = acc[mi][ni][r] + bb;
                if (OUT_BF16) ((unsigned short*)Cp)[(size_t)m * ldc + n] = f2bf(v);
                else          ((float*)Cp)[(size_t)m * ldc + n] = v;
            }
        }
    }
}

// ---------------------------------------------------------------------------
// Split-fp32 GEMM (for i2h: gathered fp32 A, K=300)
// ---------------------------------------------------------------------------
template<bool GATHER>
__global__ __launch_bounds__(256)
void gemm_split_kernel(const float* __restrict__ A, int lda,
                       const float* __restrict__ W, int ldw,
                       const float* __restrict__ bias,
                       float* __restrict__ C, int ldc,
                       int M, int N, int K,
                       const int* __restrict__ ridx)
{
    __shared__ unsigned short sAh[128][40];
    __shared__ unsigned short sAl[128][40];
    __shared__ unsigned short sWh[128][40];
    __shared__ unsigned short sWl[128][40];
    const int tid = threadIdx.x;
    const int m0 = blockIdx.y * 128;
    const int n0 = blockIdx.x * 128;
    const int wave = tid >> 6, lane = tid & 63;
    const int wm = wave >> 1, wn = wave & 1;
    const int lrow = lane & 15, lkg = lane >> 4;

    f32x4 acc[4][4];
    #pragma unroll
    for (int mi = 0; mi < 4; ++mi)
        #pragma unroll
        for (int ni = 0; ni < 4; ++ni)
            acc[mi][ni] = (f32x4){0.f, 0.f, 0.f, 0.f};

    for (int k0 = 0; k0 < K; k0 += 32) {
        for (int g = tid; g < 512; g += 256) {
            const int r = g >> 2, q = g & 3;
            const int k = k0 + q * 8;
            short8 vh = (short8){0,0,0,0,0,0,0,0};
            short8 vl = (short8){0,0,0,0,0,0,0,0};
            const int m = m0 + r;
            if (m < M && k < K) {
                const int row = GATHER ? ridx[m] : m;
                const float* src = A + (size_t)row * lda + k;
                float va[8];
                #pragma unroll
                for (int j = 0; j < 8; ++j) va[j] = (k + j < K) ? src[j] : 0.f;
                #pragma unroll
                for (int j = 0; j < 8; ++j) {
                    const unsigned short hi = f2bf(va[j]);
                    ((short*)&vh)[j] = (short)hi;
                    ((short*)&vl)[j] = (short)f2bf(va[j] - bf2f(hi));
                }
            }
            *(short8*)&sAh[r][q * 8] = vh;
            *(short8*)&sAl[r][q * 8] = vl;
        }
        for (int g = tid; g < 512; g += 256) {
            const int r = g >> 2, q = g & 3;
            const int k = k0 + q * 8;
            short8 vh = (short8){0,0,0,0,0,0,0,0};
            short8 vl = (short8){0,0,0,0,0,0,0,0};
            const int n = n0 + r;
            if (n < N && k < K) {
                const float* src = W + (size_t)n * ldw + k;
                float va[8];
                #pragma unroll
                for (int j = 0; j < 8; ++j) va[j] = (k + j < K) ? src[j] : 0.f;
                #pragma unroll
                for (int j = 0; j < 8; ++j) {
                    const unsigned short hi = f2bf(va[j]);
                    ((short*)&vh)[j] = (short)hi;
                    ((short*)&vl)[j] = (short)f2bf(va[j] - bf2f(hi));
                }
            }
            *(short8*)&sWh[r][q * 8] = vh;
            *(short8*)&sWl[r][q * 8] = vl;
        }
        __syncthreads();

        short8 ah[4], al[4], bh[4], bl[4];
        #pragma unroll
        for (int mi = 0; mi < 4; ++mi) {
            ah[mi] = *(const short8*)&sAh[wm * 64 + mi * 16 + lrow][lkg * 8];
            al[mi] = *(const short8*)&sAl[wm * 64 + mi * 16 + lrow][lkg * 8];
        }
        #pragma unroll
        for (int ni = 0; ni < 4; ++ni) {
            bh[ni] = *(const short8*)&sWh[wn * 64 + ni * 16 + lrow][lkg * 8];
            bl[ni] = *(const short8*)&sWl[wn * 64 + ni * 16 + lrow][lkg * 8];
        }
        #pragma unroll
        for (int mi = 0; mi < 4; ++mi)
            #pragma unroll
            for (int ni = 0; ni < 4; ++ni) {
                acc[mi][ni] = __builtin_amdgcn_mfma_f32_16x16x32_bf16(ah[mi], bh[ni], acc[mi][ni], 0, 0, 0);
                acc[mi][ni] = __builtin_amdgcn_mfma_f32_16x16x32_bf16(ah[mi], bl[ni], acc[mi][ni], 0, 0, 0);
                acc[mi][ni] = __builtin_amdgcn_mfma_f32_16x16x32_bf16(al[mi], bh[ni], acc[mi][ni], 0, 0, 0);
            }
        __syncthreads();
    }

    #pragma unroll
    for (int mi = 0; mi < 4; ++mi) {
        const int mbase = m0 + wm * 64 + mi * 16 + lkg * 4;
        #pragma unroll
        for (int ni = 0; ni < 4; ++ni) {
            const int n = n0 + wn * 64 + ni * 16 + lrow;
            if (n >= N) continue;
            const float bb = bias ? bias[n] : 0.f;
            #pragma unroll
            for (int r = 0; r < 4; ++r) {
                const int m = mbase + r;
                if (m >= M) continue;
                C[(size_t)m * ldc + n] = acc[mi][ni][r] + bb;
            }
        }
    }
}

// ---------------------------------------------------------------------------
// K1: att_h (in-LDS) + e + softmax -> w_buf. One block per b, 512 threads.
// att_h: 8-lane group per j (coalesced 128B chunks, L2-resident weights).
// ---------------------------------------------------------------------------
__global__ __launch_bounds__(512)
void att_front_kernel(const float* __restrict__ h_in,
                      const float* __restrict__ h2att_w,
                      const float* __restrict__ h2att_b,
                      const unsigned short* __restrict__ p_att_bf,
                      const float* __restrict__ alpha_w,
                      float* __restrict__ w_buf)
{
    const int b = blockIdx.x;
    const int tid = threadIdx.x;
    const int wave = tid >> 6, lane = tid & 63;
    const int g = lane >> 3, s = lane & 7;
    __shared__ float hs[1024];
    __shared__ float ahT[8][64];
    __shared__ float awT[8][64];
    __shared__ float esm[kL];
    __shared__ float red2[2];

    if (tid < 256) ((float4*)hs)[tid] = ((const float4*)(h_in + b * kR))[tid];
    awT[tid & 7][tid >> 3] = alpha_w[tid];
    __syncthreads();

    // att_h: wave handles 64 j's as 8 passes x 8 parallel j (8-lane k-split)
    for (int p = 0; p < 8; ++p) {
        const int j = wave * 64 + p * 8 + g;
        const float4* wr = (const float4*)(h2att_w + (size_t)j * kR);
        float a = 0.f;
        #pragma unroll 8
        for (int it = 0; it < 32; ++it) {
            const float4 wv = wr[s + it * 8];
            const float4 hv = ((const float4*)hs)[s + it * 8];
            a += wv.x * hv.x + wv.y * hv.y + wv.z * hv.z + wv.w * hv.w;
        }
        a += __shfl_xor(a, 1, 64);
        a += __shfl_xor(a, 2, 64);
        a += __shfl_xor(a, 4, 64);
        if (s == 0) ahT[j & 7][j >> 3] = a + h2att_b[j];
    }
    __syncthreads();

    // e: wave handles l = wave, wave+8, ...  (h = lane*8 + j)
    for (int l = wave; l < kL; l += 8) {
        const short8 pv = *(const short8*)(p_att_bf + ((size_t)b * kL + l) * kH + lane * 8);
        float a = 0.f;
        #pragma unroll
        for (int j = 0; j < 8; ++j)
            a += fast_tanh(bf2f(((const unsigned short*)&pv)[j]) + ahT[j][lane]) * awT[j][lane];
        #pragma unroll
        for (int off = 32; off; off >>= 1) a += __shfl_xor(a, off, 64);
        if (lane == 0) esm[l] = a;
    }
    __syncthreads();

    if (wave == 0) {
        float m = -1e30f;
        for (int l = lane; l < kL; l += 64) m = fmaxf(m, esm[l]);
        #pragma unroll
        for (int off = 32; off; off >>= 1) m = fmaxf(m, __shfl_xor(m, off, 64));
        float ssum = 0.f;
        for (int l = lane; l < kL; l += 64) ssum += __expf(esm[l] - m);
        #pragma unroll
        for (int off = 32; off; off >>= 1) ssum += __shfl_xor(ssum, off, 64);
        if (lane == 0) { red2[0] = m; red2[1] = 1.f / ssum; }
    }
    __syncthreads();
    if (tid < kL) w_buf[b * kL + tid] = __expf(esm[tid] - red2[0]) * red2[1];
}

// ---------------------------------------------------------------------------
// K2: readout. grid (4 fc, 64 b) = 256 blocks; thread owns 2 f-cols.
// att_res_bf[b,f] = sum_l w[l] * af_bf[b,l,f]
// ---------------------------------------------------------------------------
__global__ __launch_bounds__(256)
void att_readout_kernel(const float* __restrict__ w_buf,
                        const unsigned short* __restrict__ af_bf,
                        unsigned short* __restrict__ att_res_bf)
{
    const int fc = blockIdx.x, b = blockIdx.y;
    const int tid = threadIdx.x;
    __shared__ float wsm[kL];
    if (tid < kL) wsm[tid] = w_buf[b * kL + tid];
    __syncthreads();
    const int col = fc * 512 + tid * 2;
    float a0 = 0.f, a1 = 0.f;
    const unsigned short* base = af_bf + (size_t)b * kL * kF + col;
    #pragma unroll 4
    for (int l = 0; l < kL; ++l) {
        const ushort2 v = *(const ushort2*)(base + (size_t)l * kF);
        const float wl = wsm[l];
        a0 += wl * bf2f(v.x);
        a1 += wl * bf2f(v.y);
    }
    ushort2 o;
    o.x = f2bf(a0); o.y = f2bf(a1);
    *(ushort2*)(att_res_bf + (size_t)b * kF + col) = o;
}

// ---------------------------------------------------------------------------
// Fused LSTM step (h2h + a2c(bf16 att_res) + i2h_pre + gates).
// 512 blocks x 2 r-cols. Writes h_out fp32 and h_all hi/lo bf16.
// ---------------------------------------------------------------------------
__global__ __launch_bounds__(256)
void lstm_fused_kernel(const float* __restrict__ h_in,
                       const unsigned short* __restrict__ ares_bf,
                       const float* __restrict__ i2h_pre,
                       const float* __restrict__ h2h_w,
                       const float* __restrict__ h2h_b,
                       const float* __restrict__ a2c_w,
                       const float* __restrict__ a2c_b,
                       float* __restrict__ h_out,
                       float* __restrict__ cbuf,
                       unsigned short* __restrict__ h_all_hi,
                       unsigned short* __restrict__ h_all_lo,
                       int t)
{
    __shared__ float hs[64][68];
    __shared__ float ws[10][68];
    const int blk = blockIdx.x;
    const int tid = threadIdx.x;
    const int bq = tid >> 4, s = tid & 15;
    const int rc0 = blk * 2;
    const int kk = s * 4;
    float acc[4][10];
    #pragma unroll
    for (int i = 0; i < 4; ++i)
        #pragma unroll
        for (int rw = 0; rw < 10; ++rw) acc[i][rw] = 0.f;

    for (int k0 = 0; k0 < kR; k0 += 64) {
        for (int i = tid; i < 1024; i += 256) {
            const int bl = i >> 4, c4 = (i & 15) * 4;
            *(float4*)&hs[bl][c4] = *(const float4*)&h_in[bl * kR + k0 + c4];
        }
        for (int i = tid; i < 160; i += 256) {
            const int rw = i >> 4, c4 = (i & 15) * 4;
            *(float4*)&ws[rw][c4] =
                *(const float4*)&h2h_w[(size_t)((rw >> 1) * kR + rc0 + (rw & 1)) * kR + k0 + c4];
        }
        __syncthreads();
        float4 hv[4];
        #pragma unroll
        for (int i = 0; i < 4; ++i) hv[i] = *(const float4*)&hs[bq * 4 + i][kk];
        #pragma unroll
        for (int rw = 0; rw < 10; ++rw) {
            const float4 wv = *(const float4*)&ws[rw][kk];
            #pragma unroll
            for (int i = 0; i < 4; ++i)
                acc[i][rw] += hv[i].x * wv.x + hv[i].y * wv.y + hv[i].z * wv.z + hv[i].w * wv.w;
        }
        __syncthreads();
    }
    for (int k0 = 0; k0 < kF; k0 += 64) {
        for (int i = tid; i < 1024; i += 256) {
            const int bl = i >> 4, c4 = (i & 15) * 4;
            const ushort4 v = *(const ushort4*)&ares_bf[(size_t)bl * kF + k0 + c4];
            *(float4*)&hs[bl][c4] = make_float4(bf2f(v.x), bf2f(v.y), bf2f(v.z), bf2f(v.w));
        }
        for (int i = tid; i < 64; i += 256) {
            const int rw = i >> 4, c4 = (i & 15) * 4;
            *(float4*)&ws[rw][c4] =
                *(const float4*)&a2c_w[(size_t)((rw >> 1) * kR + rc0 + (rw & 1)) * kF + k0 + c4];
        }
        __syncthreads();
        float4 av[4];
        #pragma unroll
        for (int i = 0; i < 4; ++i) av[i] = *(const float4*)&hs[bq * 4 + i][kk];
        #pragma unroll
        for (int rw = 0; rw < 4; ++rw) {
            const float4 wv = *(const float4*)&ws[rw][kk];
            #pragma unroll
            for (int i = 0; i < 4; ++i)
                acc[i][6 + rw] += av[i].x * wv.x + av[i].y * wv.y + av[i].z * wv.z + av[i].w * wv.w;
        }
        __syncthreads();
    }
    #pragma unroll
    for (int i = 0; i < 4; ++i)
        #pragma unroll
        for (int rw = 0; rw < 10; ++rw) {
            float v = acc[i][rw];
            v += __shfl_xor(v, 1, 64); v += __shfl_xor(v, 2, 64);
            v += __shfl_xor(v, 4, 64); v += __shfl_xor(v, 8, 64);
            acc[i][rw] = v;
        }
    if (s == 0) {
        #pragma unroll
        for (int i = 0; i < 4; ++i) {
            const int b = bq * 4 + i;
            const float* ib = i2h_pre + (size_t)(b * kT + t) * (5 * kR);
            #pragma unroll
            for (int rr = 0; rr < 2; ++rr) {
                const int r = rc0 + rr;
                const float S0 = acc[i][0 + rr] + ib[r]          + h2h_b[r];
                const float S1 = acc[i][2 + rr] + ib[kR + r]     + h2h_b[kR + r];
                const float S2 = acc[i][4 + rr] + ib[2 * kR + r] + h2h_b[2 * kR + r];
                const float S3 = acc[i][6 + rr] + ib[3 * kR + r] + h2h_b[3 * kR + r] + a2c_b[r];
                const float S4 = acc[i][8 + rr] + ib[4 * kR + r] + h2h_b[4 * kR + r] + a2c_b[kR + r];
                const float ing = fast_sig(S0);
                const float fg  = fast_sig(S1);
                const float og  = fast_sig(S2);
                const float gg  = fmaxf(S3, S4);
                const float nc  = fg * cbuf[b * kR + r] + ing * gg;
                const float nh  = og * fast_tanh(nc);
                cbuf[b * kR + r] = nc;
                h_out[b * kR + r] = nh;
                const size_t hidx = (size_t)(b * kT + t) * kR + r;
                const unsigned short hi = f2bf(nh);
                h_all_hi[hidx] = hi;
                h_all_lo[hidx] = f2bf(nh - bf2f(hi));
            }
        }
    }
}

// ---------------------------------------------------------------------------
// in-place log_softmax over V; one block per row. Online max/sum (2 passes).
// ---------------------------------------------------------------------------
__global__ __launch_bounds__(256)
void log_softmax_kernel(float* __restrict__ out)
{
    __shared__ float mred[256];
    __shared__ float sred[256];
    const int tid = threadIdx.x;
    float* row = out + (size_t)blockIdx.x * kV;

    float m = -1e30f, s = 0.f;
    for (int v = tid; v < kV; v += 256) {
        const float x = row[v];
        if (x > m) { s = s * __expf(m - x) + 1.f; m = x; }
        else        s += __expf(x - m);
    }
    mred[tid] = m; sred[tid] = s; __syncthreads();
    for (int st = 128; st > 0; st >>= 1) {
        if (tid < st) {
            const float m2 = mred[tid + st], s2 = sred[tid + st];
            const float M = fmaxf(mred[tid], m2);
            sred[tid] = sred[tid] * __expf(mred[tid] - M) + s2 * __expf(m2 - M);
            mred[tid] = M;
        }
        __syncthreads();
    }
    const float ls = mred[0] + logf(sred[0]);
    for (int v = tid; v < kV; v += 256) row[v] -= ls;
}

extern "C" void kernel_launch(void* const* d_in, const int* in_sizes, int n_in,
                              void* d_out, int out_size, void* d_ws, size_t ws_size,
                              hipStream_t stream)
{
    const int*   seq       = (const int*)  d_in[0];
    const float* att_feats = (const float*)d_in[1];
    const float* embed_w   = (const float*)d_in[2];
    const float* ctx2att_w = (const float*)d_in[3];
    const float* ctx2att_b = (const float*)d_in[4];
    const float* h2att_w   = (const float*)d_in[5];
    const float* h2att_b   = (const float*)d_in[6];
    const float* alpha_w   = (const float*)d_in[7];
    const float* i2h_w     = (const float*)d_in[9];
    const float* i2h_b     = (const float*)d_in[10];
    const float* h2h_w     = (const float*)d_in[11];
    const float* h2h_b     = (const float*)d_in[12];
    const float* a2c_w     = (const float*)d_in[13];
    const float* a2c_b     = (const float*)d_in[14];
    const float* logit_w   = (const float*)d_in[15];
    const float* logit_b   = (const float*)d_in[16];
    float* out = (float*)d_out;

    float* ws = (float*)d_ws;
    size_t off = 0;
    auto alloc = [&](size_t nf) { float* p = ws + off; off += (nf + 3) & ~(size_t)3; return p; };

    unsigned short* af_bf      = (unsigned short*)alloc((size_t)kB * kL * kF / 2);  // 51 MB
    unsigned short* p_att_bf   = (unsigned short*)alloc((size_t)kB * kL * kH / 2);  // 12.8 MB
    unsigned short* ctx_hi     = (unsigned short*)alloc((size_t)kH * kF / 2);
    unsigned short* ctx_lo     = (unsigned short*)alloc((size_t)kH * kF / 2);
    unsigned short* logit_hi   = (unsigned short*)alloc((size_t)kV * kR / 2);
    unsigned short* logit_lo   = (unsigned short*)alloc((size_t)kV * kR / 2);
    unsigned short* h_all_hi   = (unsigned short*)alloc((size_t)kB * kT * kR / 2);
    unsigned short* h_all_lo   = (unsigned short*)alloc((size_t)kB * kT * kR / 2);
    unsigned short* att_res_bf = (unsigned short*)alloc((size_t)kB * kF / 2);
    float* i2h_pre = alloc((size_t)kB * kT * 5 * kR);   // 26 MB
    float* w_buf   = alloc((size_t)kB * kL);
    float* h0      = alloc((size_t)kB * kR);
    float* h1      = alloc((size_t)kB * kR);
    float* cbuf    = alloc((size_t)kB * kR);

    hipMemsetAsync(h0,   0, (size_t)kB * kR * sizeof(float), stream);
    hipMemsetAsync(cbuf, 0, (size_t)kB * kR * sizeof(float), stream);

    // one-time conversions
    conv_hi_kernel<<<2048, 256, 0, stream>>>(att_feats, af_bf, kB * kL * kF / 4);
    conv_pair_kernel<<<512, 256, 0, stream>>>(ctx2att_w, ctx_hi, ctx_lo, kH * kF / 4);
    conv_pair_kernel<<<2048, 256, 0, stream>>>(logit_w, logit_hi, logit_lo, kV * kR / 4);

    // p_att = att_feats(hi) @ ctx2att(hi/lo).T + b -> bf16   (12544 x 512, K=2048)
    gemm_bf_kernel<false, true><<<dim3(kH / 128, kB * kL / 128), 256, 0, stream>>>(
        af_bf, nullptr, kF, ctx_hi, ctx_lo, kF, ctx2att_b, p_att_bf, kH,
        kB * kL, kH, kF);

    // i2h_pre = embed[seq] @ i2h_w.T + b   (1280 x 5120, K=300)
    gemm_split_kernel<true><<<dim3(5 * kR / 128, kB * kT / 128), 256, 0, stream>>>(
        embed_w, kE, i2h_w, kE, i2h_b, i2h_pre, 5 * kR, kB * kT, 5 * kR, kE, seq);

    // 20-step recurrence: 3 launches per step
    float* hin = h0;
    float* hout = h1;
    for (int t = 0; t < kT; ++t) {
        att_front_kernel<<<dim3(kB), 512, 0, stream>>>(
            hin, h2att_w, h2att_b, p_att_bf, alpha_w, w_buf);
        att_readout_kernel<<<dim3(4, kB), 256, 0, stream>>>(
            w_buf, af_bf, att_res_bf);
        lstm_fused_kernel<<<dim3(512), 256, 0, stream>>>(
            hin, att_res_bf, i2h_pre, h2h_w, h2h_b, a2c_w, a2c_b,
            hout, cbuf, h_all_hi, h_all_lo, t);
        float* tmp = hin; hin = hout; hout = tmp;
    }

    // logits = h_all(hi/lo) @ logit(hi/lo).T + b -> out fp32  (1280 x 12001, K=1024)
    gemm_bf_kernel<true, false><<<dim3((kV + 127) / 128, kB * kT / 128), 256, 0, stream>>>(
        h_all_hi, h_all_lo, kR, logit_hi, logit_lo, kR, logit_b, out, kV,
        kB * kT, kV, kR);

    log_softmax_kernel<<<dim3(kB * kT), 256, 0, stream>>>(out);
}